// Round 3
// baseline (78.336 us; speedup 1.0000x reference)
//
#include <hip/hip_runtime.h>
#include <hip/hip_bf16.h>

// SpeakerEmbedder: token histogram (bag-of-words mean) -> 3-layer MLP -> L2 normalize.
// B=64, T=16384, VOCAB=1024, HIDDEN=512, EMBED=256. All math in fp32.

#define VOCAB 1024
#define HIDDEN 512
#define EMBED 256
#define TOK_T 16384
#define BATCH 64

// ---------------------------------------------------------------------------
// Kernel 1: per-row token histogram -> pooled[b][v] = count(v)/T
// One block per batch row; LDS histogram with atomics; int4-vectorized reads.
// ---------------------------------------------------------------------------
__global__ __launch_bounds__(256) void hist_kernel(const int* __restrict__ tokens,
                                                   float* __restrict__ pooled) {
    __shared__ unsigned cnt[VOCAB];
    const int tid = threadIdx.x;
#pragma unroll
    for (int i = 0; i < VOCAB / 256; ++i) cnt[tid + 256 * i] = 0u;
    __syncthreads();

    const int b = blockIdx.x;
    const int4* __restrict__ t4 = reinterpret_cast<const int4*>(tokens + (size_t)b * TOK_T);
#pragma unroll
    for (int i = 0; i < TOK_T / 4 / 256; ++i) {  // 16 iterations
        int4 v = t4[i * 256 + tid];
        atomicAdd(&cnt[v.x & (VOCAB - 1)], 1u);
        atomicAdd(&cnt[v.y & (VOCAB - 1)], 1u);
        atomicAdd(&cnt[v.z & (VOCAB - 1)], 1u);
        atomicAdd(&cnt[v.w & (VOCAB - 1)], 1u);
    }
    __syncthreads();

    const float invT = 1.0f / (float)TOK_T;
    float4 o;
    o.x = (float)cnt[tid * 4 + 0] * invT;
    o.y = (float)cnt[tid * 4 + 1] * invT;
    o.z = (float)cnt[tid * 4 + 2] * invT;
    o.w = (float)cnt[tid * 4 + 3] * invT;
    reinterpret_cast<float4*>(pooled + (size_t)b * VOCAB)[tid] = o;
}

// ---------------------------------------------------------------------------
// Kernel 2/3: dense layer out[b][j] = relu(dot(in[b][:], W[:,j]) + bias[j])
// One thread per output element. b derived from blockIdx only -> x[k] is
// wave-uniform (compiler scalarizes to s_load). W reads coalesced across j.
// ---------------------------------------------------------------------------
template <int K, int OUT, bool RELU>
__global__ __launch_bounds__(256) void dense_kernel(const float* __restrict__ in,
                                                    const float* __restrict__ W,
                                                    const float* __restrict__ bias,
                                                    float* __restrict__ out) {
    constexpr int BLOCKS_PER_ROW = OUT / 256;
    const int b = blockIdx.x / BLOCKS_PER_ROW;                       // wave-uniform
    const int j = (blockIdx.x % BLOCKS_PER_ROW) * 256 + threadIdx.x; // output column
    const float* __restrict__ x = in + (size_t)b * K;
    const float* __restrict__ w = W + j;

    float acc = bias[j];
#pragma unroll 8
    for (int k = 0; k < K; ++k) {
        acc = fmaf(x[k], w[(size_t)k * OUT], acc);
    }
    out[(size_t)b * OUT + j] = RELU ? fmaxf(acc, 0.0f) : acc;
}

// ---------------------------------------------------------------------------
// Kernel 4: final dense (512->256) + L2 normalize per row.
// One block per row, 256 threads = 256 output columns; block-reduce sum-sq.
// ---------------------------------------------------------------------------
__global__ __launch_bounds__(256) void dense3_norm_kernel(const float* __restrict__ in,
                                                          const float* __restrict__ W,
                                                          const float* __restrict__ bias,
                                                          float* __restrict__ out) {
    const int b = blockIdx.x;       // wave-uniform
    const int j = threadIdx.x;      // 0..255
    const float* __restrict__ x = in + (size_t)b * HIDDEN;
    const float* __restrict__ w = W + j;

    float acc = bias[j];
#pragma unroll 8
    for (int k = 0; k < HIDDEN; ++k) {
        acc = fmaf(x[k], w[k * EMBED], acc);
    }

    // sum of squares over all 256 threads
    float ss = acc * acc;
#pragma unroll
    for (int off = 32; off > 0; off >>= 1) ss += __shfl_down(ss, off);  // wave64 reduce

    __shared__ float wave_ss[4];
    if ((threadIdx.x & 63) == 0) wave_ss[threadIdx.x >> 6] = ss;
    __syncthreads();
    const float total = wave_ss[0] + wave_ss[1] + wave_ss[2] + wave_ss[3];

    const float norm = sqrtf(total);
    const float scale = 1.0f / fmaxf(norm, 1e-12f);  // F.normalize eps
    out[(size_t)b * EMBED + j] = acc * scale;
}

// ---------------------------------------------------------------------------
// Launch
// ---------------------------------------------------------------------------
extern "C" void kernel_launch(void* const* d_in, const int* in_sizes, int n_in,
                              void* d_out, int out_size, void* d_ws, size_t ws_size,
                              hipStream_t stream) {
    const int*   tokens = (const int*)d_in[0];   // [64,16384] (values in [0,1024))
    const float* W1     = (const float*)d_in[1]; // [1024,512]
    const float* b1     = (const float*)d_in[2]; // [512]
    const float* W2     = (const float*)d_in[3]; // [512,512]
    const float* b2     = (const float*)d_in[4]; // [512]
    const float* W3     = (const float*)d_in[5]; // [512,256]
    const float* b3     = (const float*)d_in[6]; // [256]
    float*       out    = (float*)d_out;         // [64,256]

    // Workspace layout (all fully rewritten each call): 512 KB total.
    float* pooled = (float*)d_ws;                    // 64*1024 f32
    float* h1     = pooled + (size_t)BATCH * VOCAB;  // 64*512  f32
    float* h2     = h1 + (size_t)BATCH * HIDDEN;     // 64*512  f32

    hist_kernel<<<BATCH, 256, 0, stream>>>(tokens, pooled);

    dense_kernel<VOCAB, HIDDEN, true>
        <<<BATCH * HIDDEN / 256, 256, 0, stream>>>(pooled, W1, b1, h1);

    dense_kernel<HIDDEN, HIDDEN, true>
        <<<BATCH * HIDDEN / 256, 256, 0, stream>>>(h1, W2, b2, h2);

    dense3_norm_kernel<<<BATCH, 256, 0, stream>>>(h2, W3, b3, out);
}

// Round 4
// 26.822 us; speedup vs baseline: 2.9206x; 2.9206x over previous
//
#include <hip/hip_runtime.h>
#include <hip/hip_bf16.h>

// SpeakerEmbedder: token histogram (bag-of-words mean) -> 3-layer MLP -> L2 normalize.
// B=64, T=16384, VOCAB=1024, HIDDEN=512, EMBED=256. All math in fp32.
//
// Round-3 restructure: every kernel launches >=256 blocks (1 per CU) with
// split-K inside the block (LDS reduce). x-row staged in LDS (wave-uniform
// broadcast reads); W reads coalesced across j. Dense latency was the round-2
// bottleneck (VALUBusy 2.9%, Occ 5%, 47-65us/layer).

#define VOCAB 1024
#define HIDDEN 512
#define EMBED 256
#define TOK_T 16384
#define BATCH 64
#define HSEG 4  // histogram segments per row

// ---------------------------------------------------------------------------
// Kernel 1: partial token histograms.
// Grid 256 = 64 rows x 4 segments; each block histograms T/4=4096 tokens into
// an LDS histogram, then writes raw counts to ws (counts[b][seg][v], u32).
// Conversion to pooled floats is fused into dense1's staging.
// ---------------------------------------------------------------------------
__global__ __launch_bounds__(256) void hist_kernel(const int* __restrict__ tokens,
                                                   unsigned* __restrict__ counts) {
    __shared__ unsigned cnt[VOCAB];
    const int tid = threadIdx.x;
#pragma unroll
    for (int i = 0; i < VOCAB / 256; ++i) cnt[tid + 256 * i] = 0u;
    __syncthreads();

    const int b = blockIdx.x >> 2;
    const int seg = blockIdx.x & 3;
    const int4* __restrict__ t4 =
        reinterpret_cast<const int4*>(tokens + (size_t)b * TOK_T + seg * (TOK_T / HSEG));
#pragma unroll
    for (int i = 0; i < TOK_T / HSEG / 4 / 256; ++i) {  // 4 iterations
        int4 v = t4[i * 256 + tid];
        atomicAdd(&cnt[v.x & (VOCAB - 1)], 1u);
        atomicAdd(&cnt[v.y & (VOCAB - 1)], 1u);
        atomicAdd(&cnt[v.z & (VOCAB - 1)], 1u);
        atomicAdd(&cnt[v.w & (VOCAB - 1)], 1u);
    }
    __syncthreads();

    unsigned* __restrict__ row = counts + ((size_t)b * HSEG + seg) * VOCAB;
    uint4 o;
    o.x = cnt[tid * 4 + 0];
    o.y = cnt[tid * 4 + 1];
    o.z = cnt[tid * 4 + 2];
    o.w = cnt[tid * 4 + 3];
    reinterpret_cast<uint4*>(row)[tid] = o;
}

// ---------------------------------------------------------------------------
// Kernel 2: dense layer 1 (1024 -> 512, relu), pooled computed on the fly.
// Grid 256 = 64 rows x 4 j-windows of J=128. Block 1024 thr = KG=8 x J=128.
// Stage: xs[v] = (sum of 4 partial counts) / T.  Split-K: each thread does
// KC=128 FMAs over its K-chunk; LDS reduce across the 8 k-groups.
// ---------------------------------------------------------------------------
__global__ __launch_bounds__(1024) void dense1_kernel(const unsigned* __restrict__ counts,
                                                      const float* __restrict__ W,
                                                      const float* __restrict__ bias,
                                                      float* __restrict__ out) {
    constexpr int K = VOCAB, OUT = HIDDEN, J = 128, KG = 8, KC = K / KG;
    __shared__ float xs[K];
    __shared__ float partial[KG][J];

    const int b = blockIdx.x >> 2;   // / (OUT/J)
    const int jw = blockIdx.x & 3;   // % (OUT/J)
    const int tid = threadIdx.x;

    // fused pooled staging: counts -> xs
    {
        const unsigned* __restrict__ c = counts + (size_t)b * HSEG * VOCAB;
        const int i = tid;  // NTHR == VOCAB == 1024
        unsigned s = c[i] + c[i + VOCAB] + c[i + 2 * VOCAB] + c[i + 3 * VOCAB];
        xs[i] = (float)s * (1.0f / (float)TOK_T);
    }
    __syncthreads();

    const int kg = tid >> 7;         // tid / J  (wave-uniform: J=128)
    const int jl = tid & 127;        // tid % J
    const int j = jl + jw * J;
    const float* __restrict__ w = W + (size_t)(kg * KC) * OUT + j;
    const float* __restrict__ xk = xs + kg * KC;

    float acc = 0.0f;
#pragma unroll 8
    for (int i = 0; i < KC; ++i) acc = fmaf(xk[i], w[(size_t)i * OUT], acc);

    partial[kg][jl] = acc;
    __syncthreads();

    if (tid < J) {
        float s = bias[jw * J + tid];
#pragma unroll
        for (int g = 0; g < KG; ++g) s += partial[g][tid];
        out[(size_t)b * OUT + jw * J + tid] = fmaxf(s, 0.0f);
    }
}

// ---------------------------------------------------------------------------
// Kernel 3/4: generic split-K dense layer.  Block = (KG x J) threads; grid =
// BATCH x (OUT/J).  Wave-uniform kg requires J % 64 == 0.
// ---------------------------------------------------------------------------
template <int K, int OUT, int J, int KG, bool RELU>
__global__ __launch_bounds__(J* KG) void dense_split_kernel(const float* __restrict__ in,
                                                            const float* __restrict__ W,
                                                            const float* __restrict__ bias,
                                                            float* __restrict__ out) {
    constexpr int NTHR = J * KG;
    constexpr int KC = K / KG;
    __shared__ float xs[K];
    __shared__ float partial[KG][J];

    const int b = blockIdx.x / (OUT / J);
    const int jw = blockIdx.x % (OUT / J);
    const int tid = threadIdx.x;

    const float* __restrict__ x = in + (size_t)b * K;
    for (int i = tid; i < K; i += NTHR) xs[i] = x[i];
    __syncthreads();

    const int kg = tid / J;          // wave-uniform (J multiple of 64)
    const int jl = tid % J;
    const int j = jl + jw * J;
    const float* __restrict__ w = W + (size_t)(kg * KC) * OUT + j;
    const float* __restrict__ xk = xs + kg * KC;

    float acc = 0.0f;
#pragma unroll 8
    for (int i = 0; i < KC; ++i) acc = fmaf(xk[i], w[(size_t)i * OUT], acc);

    partial[kg][jl] = acc;
    __syncthreads();

    if (tid < J) {
        float s = bias[jw * J + tid];
#pragma unroll
        for (int g = 0; g < KG; ++g) s += partial[g][tid];
        float v = RELU ? fmaxf(s, 0.0f) : s;
        out[(size_t)b * OUT + jw * J + tid] = v;
    }
}

// ---------------------------------------------------------------------------
// Kernel 5: L2 normalize rows of emb [64][256] -> out.
// ---------------------------------------------------------------------------
__global__ __launch_bounds__(256) void norm_kernel(const float* __restrict__ emb,
                                                   float* __restrict__ out) {
    const int b = blockIdx.x;
    const int j = threadIdx.x;
    const float v = emb[(size_t)b * EMBED + j];

    float ss = v * v;
#pragma unroll
    for (int off = 32; off > 0; off >>= 1) ss += __shfl_down(ss, off);  // wave64

    __shared__ float wss[4];
    if ((j & 63) == 0) wss[j >> 6] = ss;
    __syncthreads();
    const float total = wss[0] + wss[1] + wss[2] + wss[3];

    out[(size_t)b * EMBED + j] = v / fmaxf(sqrtf(total), 1e-12f);  // F.normalize eps
}

// ---------------------------------------------------------------------------
// Launch
// ---------------------------------------------------------------------------
extern "C" void kernel_launch(void* const* d_in, const int* in_sizes, int n_in,
                              void* d_out, int out_size, void* d_ws, size_t ws_size,
                              hipStream_t stream) {
    const int*   tokens = (const int*)d_in[0];   // [64,16384], values in [0,1024)
    const float* W1     = (const float*)d_in[1]; // [1024,512]
    const float* b1     = (const float*)d_in[2]; // [512]
    const float* W2     = (const float*)d_in[3]; // [512,512]
    const float* b2     = (const float*)d_in[4]; // [512]
    const float* W3     = (const float*)d_in[5]; // [512,256]
    const float* b3     = (const float*)d_in[6]; // [256]
    float*       out    = (float*)d_out;         // [64,256]

    // Workspace (fully rewritten every call): counts 1 MB + h1/h2 128 KB ea + emb 64 KB.
    unsigned* counts = (unsigned*)d_ws;                         // [64][4][1024] u32
    float*    h1     = (float*)(counts + (size_t)BATCH * HSEG * VOCAB);  // [64][512]
    float*    h2     = h1 + (size_t)BATCH * HIDDEN;                      // [64][512]
    float*    emb    = h2 + (size_t)BATCH * HIDDEN;                      // [64][256]

    hist_kernel<<<BATCH * HSEG, 256, 0, stream>>>(tokens, counts);

    dense1_kernel<<<BATCH * (HIDDEN / 128), 1024, 0, stream>>>(counts, W1, b1, h1);

    dense_split_kernel<HIDDEN, HIDDEN, 128, 8, true>
        <<<BATCH * (HIDDEN / 128), 1024, 0, stream>>>(h1, W2, b2, h2);

    dense_split_kernel<HIDDEN, EMBED, 64, 8, false>
        <<<BATCH * (EMBED / 64), 512, 0, stream>>>(h2, W3, b3, emb);

    norm_kernel<<<BATCH, 256, 0, stream>>>(emb, out);
}

// Round 5
// 26.368 us; speedup vs baseline: 2.9708x; 1.0172x over previous
//
#include <hip/hip_runtime.h>
#include <hip/hip_bf16.h>

// SpeakerEmbedder: token histogram (bag-of-words mean) -> 3-layer MLP -> L2 normalize.
// B=64, T=16384, VOCAB=1024, HIDDEN=512, EMBED=256. All math in fp32.
//
// Round-4: dense layers were L2-link-bound on W traffic (zero row reuse:
// 64 rows x 2MB = 128MB for W1). Register-block R=4 rows x C=2 cols per
// thread: x staged transposed in LDS as float4[K] (1 ds_read_b128 broadcast
// = 4 rows), 8 FMA per float2 W load. W traffic /4; grids stay >=128 blocks.

#define VOCAB 1024
#define HIDDEN 512
#define EMBED 256
#define TOK_T 16384
#define BATCH 64
#define HSEG 4  // histogram segments per row

// ---------------------------------------------------------------------------
// Kernel 1: partial token histograms.
// Grid 256 = 64 rows x 4 segments; each block histograms T/4=4096 tokens into
// an LDS histogram, writes raw counts[b][seg][v] (u32) to ws. The counts ->
// pooled conversion is fused into dense1's staging.
// ---------------------------------------------------------------------------
__global__ __launch_bounds__(256) void hist_kernel(const int* __restrict__ tokens,
                                                   unsigned* __restrict__ counts) {
    __shared__ unsigned cnt[VOCAB];
    const int tid = threadIdx.x;
#pragma unroll
    for (int i = 0; i < VOCAB / 256; ++i) cnt[tid + 256 * i] = 0u;
    __syncthreads();

    const int b = blockIdx.x >> 2;
    const int seg = blockIdx.x & 3;
    const int4* __restrict__ t4 =
        reinterpret_cast<const int4*>(tokens + (size_t)b * TOK_T + seg * (TOK_T / HSEG));
#pragma unroll
    for (int i = 0; i < TOK_T / HSEG / 4 / 256; ++i) {  // 4 iterations
        int4 v = t4[i * 256 + tid];
        atomicAdd(&cnt[v.x & (VOCAB - 1)], 1u);
        atomicAdd(&cnt[v.y & (VOCAB - 1)], 1u);
        atomicAdd(&cnt[v.z & (VOCAB - 1)], 1u);
        atomicAdd(&cnt[v.w & (VOCAB - 1)], 1u);
    }
    __syncthreads();

    unsigned* __restrict__ row = counts + ((size_t)b * HSEG + seg) * VOCAB;
    uint4 o;
    o.x = cnt[tid * 4 + 0];
    o.y = cnt[tid * 4 + 1];
    o.z = cnt[tid * 4 + 2];
    o.w = cnt[tid * 4 + 3];
    reinterpret_cast<uint4*>(row)[tid] = o;
}

// ---------------------------------------------------------------------------
// Row-blocked dense layer: out[b][j] = act(dot(x[b], W[:,j]) + bias[j]).
// Block: 256 threads = KG(16) k-groups x JT(16) j-threads.
// Block tile: R=4 rows x 32 cols; thread tile: 4 rows x 2 cols.
// Grid: (BATCH/4) row-groups x (OUT/32) j-windows.
// x staged in LDS transposed as float4 xs4[k] = {x[r0..r3][k]} -> one
// ds_read_b128 broadcast per k serves the whole 4-row tile (W reuse x4).
// FROM_COUNTS: input is u32 counts[64][4][VOCAB]; pooled = segsum/T on the fly.
// ---------------------------------------------------------------------------
template <int K, int OUT, bool RELU, bool FROM_COUNTS>
__global__ __launch_bounds__(256) void dense_rb_kernel(const void* __restrict__ in,
                                                       const float* __restrict__ W,
                                                       const float* __restrict__ bias,
                                                       float* __restrict__ out) {
    constexpr int KG = 16;
    constexpr int KC = K / KG;    // k per thread
    constexpr int JW = OUT / 32;  // j-windows
    __shared__ float4 xs4[K];                // x transposed: [k][4 rows]
    __shared__ float part[KG][4][32];        // [kg][r][jl]

    const int b0 = (blockIdx.x / JW) * 4;    // first row of this block
    const int jw = blockIdx.x % JW;
    const int tid = threadIdx.x;

    // ---- stage x (4 rows) transposed into LDS ----
    if constexpr (FROM_COUNTS) {
        const unsigned* __restrict__ c = (const unsigned*)in;
        const float invT = 1.0f / (float)TOK_T;
        for (int k = tid; k < K; k += 256) {
            float4 v;
#pragma unroll
            for (int r = 0; r < 4; ++r) {
                const unsigned* __restrict__ cr = c + (size_t)(b0 + r) * HSEG * VOCAB;
                unsigned s = cr[k] + cr[k + VOCAB] + cr[k + 2 * VOCAB] + cr[k + 3 * VOCAB];
                (&v.x)[r] = (float)s * invT;
            }
            xs4[k] = v;
        }
    } else {
        const float* __restrict__ x = (const float*)in;
        for (int k = tid; k < K; k += 256) {
            float4 v;
            v.x = x[(size_t)(b0 + 0) * K + k];
            v.y = x[(size_t)(b0 + 1) * K + k];
            v.z = x[(size_t)(b0 + 2) * K + k];
            v.w = x[(size_t)(b0 + 3) * K + k];
            xs4[k] = v;
        }
    }
    __syncthreads();

    // ---- compute: thread (kg, jt) -> 4 rows x 2 cols over its K-chunk ----
    const int jt = tid & 15;   // 16 j-threads -> cols jw*32 + jt*2 (+0,+1)
    const int kg = tid >> 4;   // 16 k-groups
    const float* __restrict__ w = W + (size_t)(kg * KC) * OUT + jw * 32 + jt * 2;
    const float4* __restrict__ xk = xs4 + kg * KC;

    float2 acc0 = {0.f, 0.f}, acc1 = {0.f, 0.f}, acc2 = {0.f, 0.f}, acc3 = {0.f, 0.f};
#pragma unroll 8
    for (int ks = 0; ks < KC; ++ks) {
        const float4 xv = xk[ks];                                   // ds_read_b128 bcast
        const float2 wv = *(const float2*)(w + (size_t)ks * OUT);   // global float2
        acc0.x = fmaf(xv.x, wv.x, acc0.x); acc0.y = fmaf(xv.x, wv.y, acc0.y);
        acc1.x = fmaf(xv.y, wv.x, acc1.x); acc1.y = fmaf(xv.y, wv.y, acc1.y);
        acc2.x = fmaf(xv.z, wv.x, acc2.x); acc2.y = fmaf(xv.z, wv.y, acc2.y);
        acc3.x = fmaf(xv.w, wv.x, acc3.x); acc3.y = fmaf(xv.w, wv.y, acc3.y);
    }

    part[kg][0][jt * 2] = acc0.x; part[kg][0][jt * 2 + 1] = acc0.y;
    part[kg][1][jt * 2] = acc1.x; part[kg][1][jt * 2 + 1] = acc1.y;
    part[kg][2][jt * 2] = acc2.x; part[kg][2][jt * 2 + 1] = acc2.y;
    part[kg][3][jt * 2] = acc3.x; part[kg][3][jt * 2 + 1] = acc3.y;
    __syncthreads();

    // ---- reduce 16 k-groups, add bias, activation, store ----
    if (tid < 128) {
        const int r = tid >> 5;        // 0..3
        const int jl = tid & 31;       // 0..31
        float s = bias[jw * 32 + jl];
#pragma unroll
        for (int g = 0; g < KG; ++g) s += part[g][r][jl];
        if (RELU) s = fmaxf(s, 0.0f);
        out[(size_t)(b0 + r) * OUT + jw * 32 + jl] = s;
    }
}

// ---------------------------------------------------------------------------
// L2 normalize rows of emb [64][256] -> out.
// ---------------------------------------------------------------------------
__global__ __launch_bounds__(256) void norm_kernel(const float* __restrict__ emb,
                                                   float* __restrict__ out) {
    const int b = blockIdx.x;
    const int j = threadIdx.x;
    const float v = emb[(size_t)b * EMBED + j];

    float ss = v * v;
#pragma unroll
    for (int off = 32; off > 0; off >>= 1) ss += __shfl_down(ss, off);  // wave64

    __shared__ float wss[4];
    if ((j & 63) == 0) wss[j >> 6] = ss;
    __syncthreads();
    const float total = wss[0] + wss[1] + wss[2] + wss[3];

    out[(size_t)b * EMBED + j] = v / fmaxf(sqrtf(total), 1e-12f);  // F.normalize eps
}

// ---------------------------------------------------------------------------
// Launch
// ---------------------------------------------------------------------------
extern "C" void kernel_launch(void* const* d_in, const int* in_sizes, int n_in,
                              void* d_out, int out_size, void* d_ws, size_t ws_size,
                              hipStream_t stream) {
    const int*   tokens = (const int*)d_in[0];   // [64,16384], values in [0,1024)
    const float* W1     = (const float*)d_in[1]; // [1024,512]
    const float* b1     = (const float*)d_in[2]; // [512]
    const float* W2     = (const float*)d_in[3]; // [512,512]
    const float* b2     = (const float*)d_in[4]; // [512]
    const float* W3     = (const float*)d_in[5]; // [512,256]
    const float* b3     = (const float*)d_in[6]; // [256]
    float*       out    = (float*)d_out;         // [64,256]

    // Workspace (fully rewritten every call).
    unsigned* counts = (unsigned*)d_ws;                                  // [64][4][1024] u32
    float*    h1     = (float*)(counts + (size_t)BATCH * HSEG * VOCAB);  // [64][512]
    float*    h2     = h1 + (size_t)BATCH * HIDDEN;                      // [64][512]
    float*    emb    = h2 + (size_t)BATCH * HIDDEN;                      // [64][256]

    hist_kernel<<<BATCH * HSEG, 256, 0, stream>>>(tokens, counts);

    // grid = (64/4) row-groups x (OUT/32) j-windows
    dense_rb_kernel<VOCAB, HIDDEN, true, true>
        <<<(BATCH / 4) * (HIDDEN / 32), 256, 0, stream>>>(counts, W1, b1, h1);

    dense_rb_kernel<HIDDEN, HIDDEN, true, false>
        <<<(BATCH / 4) * (HIDDEN / 32), 256, 0, stream>>>(h1, W2, b2, h2);

    dense_rb_kernel<HIDDEN, EMBED, false, false>
        <<<(BATCH / 4) * (EMBED / 32), 256, 0, stream>>>(h2, W3, b3, emb);

    norm_kernel<<<BATCH, 256, 0, stream>>>(emb, out);
}